// Round 9
// baseline (2070.205 us; speedup 1.0000x reference)
//
#include <hip/hip_runtime.h>
#include <math.h>

#define BB 256
#define TT 2048
#define VOCAB 7
#define EMBD 20
#define HID 128
#define OUTD 6
#define CHUNK 64
#define NCHUNK (TT / CHUNK)

typedef _Float16 h2 __attribute__((ext_vector_type(2)));

// Single-instruction fast ops (gfx950, ~1 ULP)
__device__ __forceinline__ float v_exp2(float x) {
    float r; asm("v_exp_f32 %0, %1" : "=v"(r) : "v"(x)); return r;
}
__device__ __forceinline__ float v_rcp(float x) {
    float r; asm("v_rcp_f32 %0, %1" : "=v"(r) : "v"(x)); return r;
}
__device__ __forceinline__ float sigmoid_f(float x) {
    return v_rcp(1.0f + v_exp2(-1.44269504f * x));
}
__device__ __forceinline__ float tanh_f(float x) {
    float ax = fabsf(x);
    float t = v_exp2(-2.88539008f * ax);          // exp(-2|x|)
    float r = (1.0f - t) * v_rcp(1.0f + t);
    return __builtin_copysignf(r, x);
}

#if defined(__has_builtin)
#if __has_builtin(__builtin_amdgcn_fdot2)
#define HAS_FDOT2 1
#endif
#endif

// v_dot2_f32_f16 via builtin (scheduler-friendly), scalar fallback
__device__ __forceinline__ float dot2(h2 a, h2 b, float c) {
#ifdef HAS_FDOT2
    return __builtin_amdgcn_fdot2(a, b, c, false);
#else
    return c + (float)a.x * (float)b.x + (float)a.y * (float)b.y;
#endif
}

// One block per batch element (grid == 256 == #CUs), persistent over all T.
// 1024 threads = 16 waves = 4 waves/SIMD.
// Thread (j,r) = (tid>>3, tid&7): ALL 4 gates of unit j over h-slice [16r,16r+16).
// Weights: 4 gates x 8 h2 pairs = 32 VGPRs -> fits the 128-VGPR/16-wave budget natively.
__global__ __launch_bounds__(1024) void lstm_persist(
    const int* __restrict__ inputs, const float* __restrict__ c0,
    const float* __restrict__ W_ih, const float* __restrict__ W_hh,
    const float* __restrict__ b_ih, const float* __restrict__ b_hh,
    const float* __restrict__ W_fc, const float* __restrict__ b_fc,
    const float* __restrict__ emb, float* __restrict__ out)
{
    __shared__ float4   gtab[VOCAB][HID];     // per-token gate preacts (i,f,g,o) 14336 B
    __shared__ _Float16 hbuf[CHUNK][HID];     // h ring buffer, f16, 16384 B
    __shared__ int      toks[TT];             // ALL tokens, 8192 B
    // Occupancy shaper (validated in R8: survives via volatile guard below):
    // total LDS ~87 KB > 80 KB -> occupancy model says 1 block/CU -> 16 waves/CU
    // -> register budget 128 VGPRs. (True anyway: grid = 256 = #CUs.)
    __shared__ float    ldspad[12 * 1024];    // 48 KB

    const int tid  = threadIdx.x;
    const int b    = blockIdx.x;
    const int j    = tid >> 3;      // hidden unit 0..127
    const int r    = tid & 7;       // h slice 0..7 (16 h values each)
    const int lane = tid & 63;
    const int wave = tid >> 6;

    // ---- all tokens for this batch into LDS (2 coalesced loads/thread) ----
    toks[tid]        = inputs[(size_t)b * TT + tid];
    toks[tid + 1024] = inputs[(size_t)b * TT + tid + 1024];

    // ---- W_hh: gates 0..3 of unit j, h cols [16r,16r+16) -> 32 h2 VGPRs ----
    h2 w[4][8];
    #pragma unroll
    for (int g = 0; g < 4; ++g) {
        const float2* wp = (const float2*)(W_hh + ((size_t)(g * HID + j) * HID + r * 16));
        #pragma unroll
        for (int k = 0; k < 8; ++k) {
            float2 f = wp[k];
            h2 p; p.x = (_Float16)f.x; p.y = (_Float16)f.y;
            w[g][k] = p;
        }
    }

    // ---- token -> gate preact table (threads 0..511 build one row each) ----
    if (tid < 4 * HID) {
        const int jj = tid & (HID - 1);
        const int gg = tid >> 7;                 // gate 0..3
        const int g  = gg * HID + jj;            // W_ih row
        float wih[EMBD];
        #pragma unroll
        for (int e = 0; e < EMBD; ++e) wih[e] = W_ih[g * EMBD + e];
        float bb = b_ih[g] + b_hh[g];
        #pragma unroll
        for (int v = 0; v < VOCAB; ++v) {
            float a = bb;
            #pragma unroll
            for (int e = 0; e < EMBD; ++e) a += wih[e] * emb[v * EMBD + e];
            ((float*)&gtab[v][jj])[gg] = a;
        }
    }

    // ---- state ----
    float c = c0[b * HID + j];                   // replicated across the 8 r-lanes
    if (tid < HID) hbuf[CHUNK - 1][tid] = (_Float16)0.f;   // h(-1)=0 in slot CHUNK-1

    // ---- FC weights hoisted (lane-sliced columns) ----
    float wfc0[OUTD], wfc1[OUTD], bfc[OUTD];
    #pragma unroll
    for (int o = 0; o < OUTD; ++o) {
        wfc0[o] = W_fc[o * HID + 2 * lane];
        wfc1[o] = W_fc[o * HID + 2 * lane + 1];
        bfc[o]  = b_fc[o];
    }
    __syncthreads();

    // xg carried across steps; prefetched one step ahead (gtab is immutable)
    float4 xg = gtab[toks[0]][j];

    #pragma unroll 1
    for (int ch = 0; ch < NCHUNK; ++ch) {
        const int t0 = ch * CHUNK;

        #pragma unroll 1
        for (int s = 0; s < CHUNK; ++s) {
            const int t    = t0 + s;
            const int prev = (s + CHUNK - 1) & (CHUNK - 1);

            // h slice: 2 x ds_read_b128; 8 distinct addrs/wave, 8-lane broadcast each
            const uint4* hp = (const uint4*)&hbuf[prev][r * 16];
            uint4 v0 = hp[0], v1 = hp[1];

            float a0 = 0.f, a1 = 0.f, a2 = 0.f, a3 = 0.f;
            #pragma unroll
            for (int g = 0; g < 1; ++g) { /* keep scope flat */ }
            {
                h2 hx0 = __builtin_bit_cast(h2, v0.x), hy0 = __builtin_bit_cast(h2, v0.y);
                h2 hz0 = __builtin_bit_cast(h2, v0.z), hw0 = __builtin_bit_cast(h2, v0.w);
                h2 hx1 = __builtin_bit_cast(h2, v1.x), hy1 = __builtin_bit_cast(h2, v1.y);
                h2 hz1 = __builtin_bit_cast(h2, v1.z), hw1 = __builtin_bit_cast(h2, v1.w);
                a0 = dot2(w[0][0], hx0, a0); a0 = dot2(w[0][1], hy0, a0);
                a0 = dot2(w[0][2], hz0, a0); a0 = dot2(w[0][3], hw0, a0);
                a0 = dot2(w[0][4], hx1, a0); a0 = dot2(w[0][5], hy1, a0);
                a0 = dot2(w[0][6], hz1, a0); a0 = dot2(w[0][7], hw1, a0);
                a1 = dot2(w[1][0], hx0, a1); a1 = dot2(w[1][1], hy0, a1);
                a1 = dot2(w[1][2], hz0, a1); a1 = dot2(w[1][3], hw0, a1);
                a1 = dot2(w[1][4], hx1, a1); a1 = dot2(w[1][5], hy1, a1);
                a1 = dot2(w[1][6], hz1, a1); a1 = dot2(w[1][7], hw1, a1);
                a2 = dot2(w[2][0], hx0, a2); a2 = dot2(w[2][1], hy0, a2);
                a2 = dot2(w[2][2], hz0, a2); a2 = dot2(w[2][3], hw0, a2);
                a2 = dot2(w[2][4], hx1, a2); a2 = dot2(w[2][5], hy1, a2);
                a2 = dot2(w[2][6], hz1, a2); a2 = dot2(w[2][7], hw1, a2);
                a3 = dot2(w[3][0], hx0, a3); a3 = dot2(w[3][1], hy0, a3);
                a3 = dot2(w[3][2], hz0, a3); a3 = dot2(w[3][3], hw0, a3);
                a3 = dot2(w[3][4], hx1, a3); a3 = dot2(w[3][5], hy1, a3);
                a3 = dot2(w[3][6], hz1, a3); a3 = dot2(w[3][7], hw1, a3);
            }

            // reduce over the 8 r-lanes (xor 1,2,4) -> all lanes hold full sums
            a0 += __shfl_xor(a0, 1, 64); a0 += __shfl_xor(a0, 2, 64); a0 += __shfl_xor(a0, 4, 64);
            a1 += __shfl_xor(a1, 1, 64); a1 += __shfl_xor(a1, 2, 64); a1 += __shfl_xor(a1, 4, 64);
            a2 += __shfl_xor(a2, 1, 64); a2 += __shfl_xor(a2, 2, 64); a2 += __shfl_xor(a2, 4, 64);
            a3 += __shfl_xor(a3, 1, 64); a3 += __shfl_xor(a3, 2, 64); a3 += __shfl_xor(a3, 4, 64);

            float gi = sigmoid_f(a0 + xg.x);
            float gf = sigmoid_f(a1 + xg.y);
            float gg = tanh_f  (a2 + xg.z);
            float go = sigmoid_f(a3 + xg.w);
            c = gf * c + gi * gg;                 // replicated x8, identical values
            float h = go * tanh_f(c);
            if (r == 0) hbuf[s][j] = (_Float16)h;

            // prefetch next step's gate preacts (gtab immutable -> no race)
            xg = gtab[toks[(t + 1) & (TT - 1)]][j];
            __syncthreads();
        }

        // ---- FC + softmax flush for this chunk (16 waves x 4 rows) ----
        #pragma unroll 1
        for (int i = 0; i < CHUNK / 16; ++i) {
            const int row = wave * (CHUNK / 16) + i;   // timestep row in chunk
            h2 hv = ((const h2*)&hbuf[row][0])[lane];
            float h0 = (float)hv.x, h1 = (float)hv.y;
            float acc[OUTD];
            #pragma unroll
            for (int o = 0; o < OUTD; ++o) acc[o] = wfc0[o] * h0 + wfc1[o] * h1;
            #pragma unroll
            for (int off = 32; off >= 1; off >>= 1) {
                #pragma unroll
                for (int o = 0; o < OUTD; ++o) acc[o] += __shfl_xor(acc[o], off, 64);
            }
            if (lane == 0) {
                float m = -1e30f;
                #pragma unroll
                for (int o = 0; o < OUTD; ++o) { acc[o] += bfc[o]; m = fmaxf(m, acc[o]); }
                float e[OUTD], ssum = 0.f;
                #pragma unroll
                for (int o = 0; o < OUTD; ++o) { e[o] = v_exp2(1.44269504f * (acc[o] - m)); ssum += e[o]; }
                float inv = v_rcp(ssum);
                float* po = out + ((size_t)b * TT + (t0 + row)) * OUTD;
                #pragma unroll
                for (int o = 0; o < OUTD; ++o) po[o] = e[o] * inv;
            }
        }
        __syncthreads();
    }

    // ---- Keep ldspad allocated (validated R8): volatile LDS write+read feeding a
    // global store inside a data-dependent never-true branch (tokens are 0..6).
    if (__builtin_expect(inputs[0] == -2147483647, 0)) {
        volatile float* vp = ldspad;
        vp[tid] = (float)tid;
        out[tid] = vp[tid + 1];
    }
}

extern "C" void kernel_launch(void* const* d_in, const int* in_sizes, int n_in,
                              void* d_out, int out_size, void* d_ws, size_t ws_size,
                              hipStream_t stream) {
    const int*   inputs = (const int*)  d_in[0];
    const float* c0     = (const float*)d_in[1];
    const float* W_ih   = (const float*)d_in[2];
    const float* W_hh   = (const float*)d_in[3];
    const float* b_ih   = (const float*)d_in[4];
    const float* b_hh   = (const float*)d_in[5];
    const float* W_fc   = (const float*)d_in[6];
    const float* b_fc   = (const float*)d_in[7];
    const float* emb    = (const float*)d_in[8];
    float* out = (float*)d_out;

    lstm_persist<<<BB, 1024, 0, stream>>>(inputs, c0, W_ih, W_hh, b_ih, b_hh,
                                          W_fc, b_fc, emb, out);
}

// Round 14
// 1389.619 us; speedup vs baseline: 1.4898x; 1.4898x over previous
//
#include <hip/hip_runtime.h>
#include <math.h>

#define BB 256
#define TT 2048
#define VOCAB 7
#define EMBD 20
#define HID 128
#define OUTD 6
#define CHUNK 64
#define NCHUNK (TT / CHUNK)

typedef _Float16 h2 __attribute__((ext_vector_type(2)));

// Single-instruction fast ops (gfx950, ~1 ULP)
__device__ __forceinline__ float v_exp2(float x) {
    float r; asm("v_exp_f32 %0, %1" : "=v"(r) : "v"(x)); return r;
}
__device__ __forceinline__ float v_rcp(float x) {
    float r; asm("v_rcp_f32 %0, %1" : "=v"(r) : "v"(x)); return r;
}
__device__ __forceinline__ float sigmoid_f(float x) {
    return v_rcp(1.0f + v_exp2(-1.44269504f * x));
}
__device__ __forceinline__ float tanh_f(float x) {
    float ax = fabsf(x);
    float t = v_exp2(-2.88539008f * ax);          // exp(-2|x|)
    float r = (1.0f - t) * v_rcp(1.0f + t);
    return __builtin_copysignf(r, x);
}

#if defined(__has_builtin)
#if __has_builtin(__builtin_amdgcn_fdot2)
#define HAS_FDOT2 1
#endif
#endif

// v_dot2_f32_f16 via builtin (scheduler-friendly, clean regalloc per R9)
__device__ __forceinline__ float dot2(h2 a, h2 b, float c) {
#ifdef HAS_FDOT2
    return __builtin_amdgcn_fdot2(a, b, c, false);
#else
    return c + (float)a.x * (float)b.x + (float)a.y * (float)b.y;
#endif
}

// Quad reduction via DPP quad_perm — pure VALU, ZERO DS-pipe ops.
// 0xB1 = quad_perm[1,0,3,2] (xor1), 0x4E = quad_perm[2,3,0,1] (xor2).
__device__ __forceinline__ float qreduce(float x) {
    int t1 = __builtin_amdgcn_update_dpp(0, __builtin_bit_cast(int, x), 0xB1, 0xF, 0xF, true);
    x += __builtin_bit_cast(float, t1);
    int t2 = __builtin_amdgcn_update_dpp(0, __builtin_bit_cast(int, x), 0x4E, 0xF, 0xF, true);
    x += __builtin_bit_cast(float, t2);
    return x;
}

// One block per batch element (grid == 256 == #CUs), persistent over all T.
// 512 threads = 8 waves = 2 waves/SIMD.
// Thread (j,r) = (tid>>2, tid&3): ALL 4 gates of unit j over h-slice [32r,32r+32).
// Weights: 4 gates x 16 h2 pairs = 64 VGPRs (builtin dot2, no pins -> clean alloc).
__global__ __launch_bounds__(512) void lstm_persist(
    const int* __restrict__ inputs, const float* __restrict__ c0,
    const float* __restrict__ W_ih, const float* __restrict__ W_hh,
    const float* __restrict__ b_ih, const float* __restrict__ b_hh,
    const float* __restrict__ W_fc, const float* __restrict__ b_fc,
    const float* __restrict__ emb, float* __restrict__ out)
{
    __shared__ float4   gtab[VOCAB][HID];     // per-token gate preacts (i,f,g,o) 14336 B
    __shared__ _Float16 hbuf[CHUNK][HID];     // h ring buffer, f16, 16384 B
    __shared__ int      toks[TT];             // all tokens, 8192 B
    // Occupancy shaper (validated R8): ~135 KB static LDS -> occupancy model says
    // 1 block/CU -> 2 waves/SIMD -> register-pressure budget 256 VGPRs.
    // (True anyway: grid = 256 = #CUs.) Kept alive by volatile guard at the end.
    __shared__ float    ldspad[24 * 1024];    // 96 KB

    const int tid  = threadIdx.x;
    const int b    = blockIdx.x;
    const int j    = tid >> 2;      // hidden unit 0..127
    const int r    = tid & 3;       // h slice 0..3
    const int lane = tid & 63;
    const int wave = tid >> 6;

    // ---- all tokens for this batch into LDS (4 coalesced loads/thread) ----
    #pragma unroll
    for (int i = 0; i < TT / 512; ++i)
        toks[tid + 512 * i] = inputs[(size_t)b * TT + tid + 512 * i];

    // ---- W_hh: gates 0..3 of unit j, h cols [32r, 32r+32) -> 64 h2 VGPRs ----
    h2 w0[16], w1[16], w2[16], w3[16];
    {
        const float2* p0 = (const float2*)(W_hh + ((size_t)(0 * HID + j) * HID + r * 32));
        const float2* p1 = (const float2*)(W_hh + ((size_t)(1 * HID + j) * HID + r * 32));
        const float2* p2 = (const float2*)(W_hh + ((size_t)(2 * HID + j) * HID + r * 32));
        const float2* p3 = (const float2*)(W_hh + ((size_t)(3 * HID + j) * HID + r * 32));
        #pragma unroll
        for (int k = 0; k < 16; ++k) {
            float2 f0 = p0[k], f1 = p1[k], f2 = p2[k], f3 = p3[k];
            h2 a; a.x = (_Float16)f0.x; a.y = (_Float16)f0.y; w0[k] = a;
            h2 bq; bq.x = (_Float16)f1.x; bq.y = (_Float16)f1.y; w1[k] = bq;
            h2 cq; cq.x = (_Float16)f2.x; cq.y = (_Float16)f2.y; w2[k] = cq;
            h2 dq; dq.x = (_Float16)f3.x; dq.y = (_Float16)f3.y; w3[k] = dq;
        }
    }

    // ---- token -> gate preact table: gtab[v][j][gate r] (thread builds row g=r*128+j)
    {
        const int g = r * HID + j;
        float wih[EMBD];
        #pragma unroll
        for (int e = 0; e < EMBD; ++e) wih[e] = W_ih[g * EMBD + e];
        float bb = b_ih[g] + b_hh[g];
        #pragma unroll
        for (int v = 0; v < VOCAB; ++v) {
            float a = bb;
            #pragma unroll
            for (int e = 0; e < EMBD; ++e) a += wih[e] * emb[v * EMBD + e];
            ((float*)&gtab[v][j])[r] = a;
        }
    }

    // ---- state ----
    float c = c0[b * HID + j];      // replicated across the 4 slice lanes of unit j
    if (tid < HID) hbuf[CHUNK - 1][tid] = (_Float16)0.f;   // h(-1)=0 in slot CHUNK-1

    // ---- FC weights hoisted (lane-sliced columns) ----
    float wfc0[OUTD], wfc1[OUTD], bfc[OUTD];
    #pragma unroll
    for (int o = 0; o < OUTD; ++o) {
        wfc0[o] = W_fc[o * HID + 2 * lane];
        wfc1[o] = W_fc[o * HID + 2 * lane + 1];
        bfc[o]  = b_fc[o];
    }
    __syncthreads();

    #pragma unroll 1
    for (int ch = 0; ch < NCHUNK; ++ch) {
        const int t0 = ch * CHUNK;

        #pragma unroll 1
        for (int s = 0; s < CHUNK; ++s) {
            const int prev = (s + CHUNK - 1) & (CHUNK - 1);

            // h slice: 4 ds_read_b128, 4 distinct addrs/wave (16-lane broadcast each)
            const uint4* hp = (const uint4*)&hbuf[prev][r * 32];
            float a0 = 0.f, a1 = 0.f, a2 = 0.f, a3 = 0.f;
            #pragma unroll
            for (int k = 0; k < 4; ++k) {
                uint4 v = hp[k];
                h2 hx = __builtin_bit_cast(h2, v.x);
                h2 hy = __builtin_bit_cast(h2, v.y);
                h2 hz = __builtin_bit_cast(h2, v.z);
                h2 hw = __builtin_bit_cast(h2, v.w);
                a0 = dot2(w0[4*k+0], hx, a0); a0 = dot2(w0[4*k+1], hy, a0);
                a0 = dot2(w0[4*k+2], hz, a0); a0 = dot2(w0[4*k+3], hw, a0);
                a1 = dot2(w1[4*k+0], hx, a1); a1 = dot2(w1[4*k+1], hy, a1);
                a1 = dot2(w1[4*k+2], hz, a1); a1 = dot2(w1[4*k+3], hw, a1);
                a2 = dot2(w2[4*k+0], hx, a2); a2 = dot2(w2[4*k+1], hy, a2);
                a2 = dot2(w2[4*k+2], hz, a2); a2 = dot2(w2[4*k+3], hw, a2);
                a3 = dot2(w3[4*k+0], hx, a3); a3 = dot2(w3[4*k+1], hy, a3);
                a3 = dot2(w3[4*k+2], hz, a3); a3 = dot2(w3[4*k+3], hw, a3);
            }
            // quad reduce over the 4 h-slices — DPP (VALU), no DS-pipe traffic
            a0 = qreduce(a0); a1 = qreduce(a1);
            a2 = qreduce(a2); a3 = qreduce(a3);

            const float4 xg = gtab[toks[t0 + s]][j];   // quad-uniform b128
            float gi = sigmoid_f(a0 + xg.x);
            float gf = sigmoid_f(a1 + xg.y);
            float gg = tanh_f  (a2 + xg.z);
            float go = sigmoid_f(a3 + xg.w);
            c = gf * c + gi * gg;                 // replicated x4, identical values
            float h = go * tanh_f(c);
            if (r == 0) hbuf[s][j] = (_Float16)h;
            __syncthreads();
        }

        // ---- FC + softmax flush for this chunk ----
        #pragma unroll 1
        for (int i = 0; i < CHUNK / 8; ++i) {
            const int row = wave * (CHUNK / 8) + i;   // timestep row in chunk
            h2 hv = ((const h2*)&hbuf[row][0])[lane];
            float h0 = (float)hv.x, h1 = (float)hv.y;
            float acc[OUTD];
            #pragma unroll
            for (int o = 0; o < OUTD; ++o) acc[o] = wfc0[o] * h0 + wfc1[o] * h1;
            #pragma unroll
            for (int off = 32; off >= 1; off >>= 1) {
                #pragma unroll
                for (int o = 0; o < OUTD; ++o) acc[o] += __shfl_xor(acc[o], off, 64);
            }
            if (lane == 0) {
                float m = -1e30f;
                #pragma unroll
                for (int o = 0; o < OUTD; ++o) { acc[o] += bfc[o]; m = fmaxf(m, acc[o]); }
                float e[OUTD], ssum = 0.f;
                #pragma unroll
                for (int o = 0; o < OUTD; ++o) { e[o] = v_exp2(1.44269504f * (acc[o] - m)); ssum += e[o]; }
                float inv = v_rcp(ssum);
                float* po = out + ((size_t)b * TT + (t0 + row)) * OUTD;
                #pragma unroll
                for (int o = 0; o < OUTD; ++o) po[o] = e[o] * inv;
            }
        }
        __syncthreads();
    }

    // ---- Keep ldspad allocated (validated R8): volatile LDS write+read feeding a
    // global store inside a data-dependent never-true branch (tokens are 0..6).
    if (__builtin_expect(inputs[0] == -2147483647, 0)) {
        volatile float* vp = ldspad;
        vp[tid] = (float)tid;
        out[tid] = vp[tid + 1];
    }
}

extern "C" void kernel_launch(void* const* d_in, const int* in_sizes, int n_in,
                              void* d_out, int out_size, void* d_ws, size_t ws_size,
                              hipStream_t stream) {
    const int*   inputs = (const int*)  d_in[0];
    const float* c0     = (const float*)d_in[1];
    const float* W_ih   = (const float*)d_in[2];
    const float* W_hh   = (const float*)d_in[3];
    const float* b_ih   = (const float*)d_in[4];
    const float* b_hh   = (const float*)d_in[5];
    const float* W_fc   = (const float*)d_in[6];
    const float* b_fc   = (const float*)d_in[7];
    const float* emb    = (const float*)d_in[8];
    float* out = (float*)d_out;

    lstm_persist<<<BB, 512, 0, stream>>>(inputs, c0, W_ih, W_hh, b_ih, b_hh,
                                         W_fc, b_fc, emb, out);
}